// Round 1
// baseline (301.451 us; speedup 1.0000x reference)
//
#include <hip/hip_runtime.h>
#include <hip/hip_bf16.h>

typedef __bf16 bf16_t;
typedef bf16_t bf16x8 __attribute__((ext_vector_type(8)));
typedef bf16_t bf16x4 __attribute__((ext_vector_type(4)));
typedef float f32x4 __attribute__((ext_vector_type(4)));

#define B_   4
#define S_   1024
#define H_   32
#define KVH_ 8
#define D_   128
#define WIN_ 512
#define KVD_ (KVH_ * D_)                 // 1024
#define LOG2E_ 1.4426950408889634f
// log2-domain softcap: capL = 50*log2e*tanh(score*scale/50)
// Softcap BOUNDS the logits (|capL| <= K2_), so softmax can use a FIXED max:
//   p = exp2(capL - K2_) = exp2(-2*K2_ / (ez+1)),  ez = exp2(score*C1_)
// This is exact (same p/l ratios), and kills all online-max machinery.
#define C1_ (2.0f * (0.08838834764831845f / 50.0f) * LOG2E_)
#define K2_ (50.0f * LOG2E_)
#define NK22_ (-2.0f * K2_)
#define EXP2F_(x) __builtin_amdgcn_exp2f(x)   // __exp2f collides w/ glibc macro

// ---------------- prepass: fp32 K/V -> bf16, head-major; V transposed ------
__global__ __launch_bounds__(256) void prep_kv(
    const float* __restrict__ K, const float* __restrict__ V,
    bf16_t* __restrict__ Kb, bf16_t* __restrict__ Vt)
{
  const int j0  = blockIdx.x * 64;
  const int kvh = blockIdx.y;
  const int b   = blockIdx.z;
  const int t   = threadIdx.x;
  const int j   = t >> 2;                // token row 0..63
  const int d0  = (t & 3) * 32;
  __shared__ bf16_t tl[128][72];

  // K: straight bf16 copy into [b][kvh][s][d]
  {
    const float* src = K + (size_t)(b * S_ + j0 + j) * KVD_ + kvh * D_ + d0;
    bf16_t* dst = Kb + ((size_t)(b * KVH_ + kvh) * S_ + j0 + j) * D_ + d0;
    #pragma unroll
    for (int c = 0; c < 4; ++c) {
      float4 f0 = *(const float4*)(src + c * 8);
      float4 f1 = *(const float4*)(src + c * 8 + 4);
      bf16x8 o = { (bf16_t)f0.x, (bf16_t)f0.y, (bf16_t)f0.z, (bf16_t)f0.w,
                   (bf16_t)f1.x, (bf16_t)f1.y, (bf16_t)f1.z, (bf16_t)f1.w };
      *(bf16x8*)(dst + c * 8) = o;
    }
  }
  // V: transpose via LDS into [b][kvh][d][s]
  {
    const float* src = V + (size_t)(b * S_ + j0 + j) * KVD_ + kvh * D_ + d0;
    #pragma unroll
    for (int c = 0; c < 8; ++c) {
      float4 f = *(const float4*)(src + c * 4);
      tl[d0 + c * 4 + 0][j] = (bf16_t)f.x;
      tl[d0 + c * 4 + 1][j] = (bf16_t)f.y;
      tl[d0 + c * 4 + 2][j] = (bf16_t)f.z;
      tl[d0 + c * 4 + 3][j] = (bf16_t)f.w;
    }
  }
  __syncthreads();
  {
    const int d = t >> 1, half = (t & 1) * 32;
    bf16_t* dst = Vt + ((size_t)(b * KVH_ + kvh) * D_ + d) * S_ + j0 + half;
    #pragma unroll
    for (int c = 0; c < 4; ++c)
      *(bf16x8*)(dst + c * 8) = *(bf16x8*)&tl[d][half + c * 8];
  }
}

// ---------------- attention ------------------------------------------------
// wg = (b, kvh, 32-row q-tile), 512 thr = 8 waves = 4 heads x 2 row-blocks.
// KVBLK=32, LDS 40KB -> 3-4 blocks/CU (was 80KB -> <=2).  Staging is
// reg-based: LINEAR coalesced global dwordx4 loads issued at tile top
// (latency hides under compute), swizzled ds_write_b128 after compute,
// ONE barrier per tile publishes the buffer.  Fixed-max softmax (softcap
// bound) removes the online-max/rescale machinery entirely.
__global__ __launch_bounds__(512, 6) void attn_fwd(
    const float* __restrict__ Q, const bf16_t* __restrict__ Kb,
    const bf16_t* __restrict__ Vt, float* __restrict__ Out)
{
  // XCD-aware bijective swizzle (1024 wgs % 8 == 0): each XCD gets a
  // contiguous 128-wg chunk = 4 whole (b,kvh) heads -> 2MB K/V per L2.
  const int fid = blockIdx.x + 32 * (blockIdx.y + 8 * (int)blockIdx.z);
  const int swz = (fid & 7) * 128 + (fid >> 3);
  const int i0  = (swz & 31) * 32;
  const int kvh = (swz >> 5) & 7;
  const int b   = swz >> 8;

  const int tid  = threadIdx.x;
  const int w    = tid >> 6;
  const int lane = tid & 63;
  const int m16  = lane & 15;
  const int quad = lane >> 4;
  const int g    = w & 3;
  const int rb   = w >> 2;
  const int h    = kvh * 4 + g;
  const int iw   = i0 + rb * 16;
  const int i    = iw + m16;

  __shared__ __align__(16) bf16_t KsB[2][32 * 128];  // 8KB x2
  __shared__ __align__(16) bf16_t VtB[2][128 * 32];  // 8KB x2
  __shared__ __align__(16) bf16_t PsB[8 * 16 * 32];  // 8KB

  // Q fragments (B-operand layout)
  bf16x8 qf[4];
  {
    const float* qp = Q + ((size_t)(b * S_ + iw + m16) * H_ + h) * D_;
    #pragma unroll
    for (int s = 0; s < 4; ++s) {
      const int d0 = 32 * s + 8 * quad;
      float4 f0 = *(const float4*)(qp + d0);
      float4 f1 = *(const float4*)(qp + d0 + 4);
      bf16x8 t = { (bf16_t)f0.x, (bf16_t)f0.y, (bf16_t)f0.z, (bf16_t)f0.w,
                   (bf16_t)f1.x, (bf16_t)f1.y, (bf16_t)f1.z, (bf16_t)f1.w };
      qf[s] = t;
    }
  }

  f32x4 O[8];
  #pragma unroll
  for (int c = 0; c < 8; ++c) O[c] = (f32x4){0.f, 0.f, 0.f, 0.f};
  f32x4 lacc = (f32x4){0.f, 0.f, 0.f, 0.f};

  const bf16_t* khead = Kb + (size_t)(b * KVH_ + kvh) * S_ * D_;
  const bf16_t* vhead = Vt + (size_t)(b * KVH_ + kvh) * D_ * S_;

  // per-thread staging geometry: chunk id = tid (512 x 16B = one K or V tile)
  const int krow = tid >> 4, kpos = tid & 15;     // K: 32 rows x 16 chunks
  const int vd   = tid >> 2, vpos = tid & 3;      // V^T: 128 rows x 4 chunks
  const bf16_t* ksrc = khead + (size_t)krow * D_ + kpos * 8;  // LINEAR global
  const bf16_t* vsrc = vhead + (size_t)vd * S_ + vpos * 8;
  const int koff = krow * 128 + ((kpos ^ (krow & 15)) << 3);  // swizzled LDS
  const int voff = vd * 32 + ((vpos ^ (vd & 3)) << 3);

  const int t_lo = (i0 >= WIN_) ? ((i0 - (WIN_ - 1)) >> 5) : 0;
  const int t_hi = i0 >> 5;

  // prologue: stage tile t_lo into buffer 0
  {
    int4 kr = *(const int4*)(ksrc + (size_t)t_lo * 32 * D_);
    int4 vr = *(const int4*)(vsrc + t_lo * 32);
    *(int4*)&KsB[0][koff] = kr;
    *(int4*)&VtB[0][voff] = vr;
  }
  __syncthreads();
  int buf = 0;

  for (int tb = t_lo; tb <= t_hi; ++tb) {
    const int j0  = tb * 32;
    const bool pre = (tb < t_hi);
    int4 kr, vr;
    if (pre) {   // issue next-tile loads NOW; vmcnt naturally drains at use
      kr = *(const int4*)(ksrc + (size_t)(j0 + 32) * D_);
      vr = *(const int4*)(vsrc + (j0 + 32));
    }

    if (!(j0 > iw + 15 || j0 + 31 < iw - (WIN_ - 1))) {
      const bool full = (j0 + 31 <= iw) && (iw + 15 - j0 < WIN_);
      const int pw = w * (16 * 32);

      // ---- S^T = K·Q^T, fused softcap -> p (fixed max) -> P to LDS ----
      #pragma unroll
      for (int t4 = 0; t4 < 2; ++t4) {
        f32x4 acc = (f32x4){0.f, 0.f, 0.f, 0.f};
        const int row = 16 * t4 + m16;
        #pragma unroll
        for (int s = 0; s < 4; ++s) {
          bf16x8 a = *(const bf16x8*)&KsB[buf][row * 128 + (((quad + 4 * s) ^ m16) << 3)];
          acc = __builtin_amdgcn_mfma_f32_16x16x32_bf16(a, qf[s], acc, 0, 0, 0);
        }
        bf16x4 pk;
        #pragma unroll
        for (int r = 0; r < 4; ++r) {
          float ez = EXP2F_(acc[r] * C1_);
          float p  = EXP2F_(NK22_ * __builtin_amdgcn_rcpf(ez + 1.f));
          if (!full) {
            const int j = j0 + t4 * 16 + 4 * quad + r;
            p = ((j <= i) && (i - j < WIN_)) ? p : 0.f;
          }
          lacc[r] += p;
          pk[r] = (bf16_t)p;
        }
        const int ch = (2 * t4 + (quad >> 1)) ^ (m16 & 3);
        *(bf16x4*)&PsB[pw + m16 * 32 + ch * 8 + (quad & 1) * 4] = pk;
      }
      bf16x8 pa = *(const bf16x8*)&PsB[pw + m16 * 32 + ((quad ^ (m16 & 3)) << 3)];

      // ---- O += P·V ----
      #pragma unroll
      for (int c = 0; c < 8; ++c) {
        const int vrow = 16 * c + m16;
        bf16x8 v = *(const bf16x8*)&VtB[buf][vrow * 32 + ((quad ^ (m16 & 3)) << 3)];
        O[c] = __builtin_amdgcn_mfma_f32_16x16x32_bf16(pa, v, O[c], 0, 0, 0);
      }
    }

    if (pre) {   // write-late: regs -> swizzled LDS, published by the barrier
      *(int4*)&KsB[buf ^ 1][koff] = kr;
      *(int4*)&VtB[buf ^ 1][voff] = vr;
    }
    __syncthreads();
    buf ^= 1;
  }

  // ---- epilogue: one deferred row-sum reduce, then scale + store ----
  float l_run = lacc[0] + lacc[1] + lacc[2] + lacc[3];
  l_run += __shfl_xor(l_run, 16);
  l_run += __shfl_xor(l_run, 32);

  float* ob = Out + ((size_t)(b * S_ + iw) * H_ + h) * D_;
  #pragma unroll
  for (int r = 0; r < 4; ++r) {
    const int rr = 4 * quad + r;
    const float lr = __shfl(l_run, rr);
    const float linv = __builtin_amdgcn_rcpf(lr);
    float* po = ob + (size_t)rr * (H_ * D_);
    #pragma unroll
    for (int c = 0; c < 8; ++c) po[c * 16 + m16] = O[c][r] * linv;
  }
}

extern "C" void kernel_launch(void* const* d_in, const int* in_sizes, int n_in,
                              void* d_out, int out_size, void* d_ws, size_t ws_size,
                              hipStream_t stream) {
  const float* q = (const float*)d_in[0];
  const float* k = (const float*)d_in[1];
  const float* v = (const float*)d_in[2];
  float* out = (float*)d_out;
  const size_t nkv = (size_t)B_ * KVH_ * S_ * D_;   // 4.19M elems per tensor
  bf16_t *kb, *vt;
  if (ws_size >= 2 * nkv * sizeof(bf16_t)) {
    kb = (bf16_t*)d_ws; vt = kb + nkv;
  } else {
    // k_cache/v_cache are dead inputs (identity round-trip) - reuse as scratch
    kb = (bf16_t*)d_in[3]; vt = (bf16_t*)d_in[4];
  }
  prep_kv<<<dim3(S_ / 64, KVH_, B_), 256, 0, stream>>>(k, v, kb, vt);
  attn_fwd<<<dim3(S_ / 32, KVH_, B_), 512, 0, stream>>>(q, kb, vt, out);
}

// Round 2
// 210.724 us; speedup vs baseline: 1.4305x; 1.4305x over previous
//
#include <hip/hip_runtime.h>
#include <hip/hip_bf16.h>

typedef __bf16 bf16_t;
typedef bf16_t bf16x8 __attribute__((ext_vector_type(8)));
typedef bf16_t bf16x4 __attribute__((ext_vector_type(4)));
typedef float f32x4 __attribute__((ext_vector_type(4)));

#define B_   4
#define S_   1024
#define H_   32
#define KVH_ 8
#define D_   128
#define WIN_ 512
#define KVD_ (KVH_ * D_)                 // 1024
#define LOG2E_ 1.4426950408889634f
// log2-domain softcap: capL = 50*log2e*tanh(score*scale/50)
// Softcap BOUNDS the logits (|capL| <= K2_), so softmax can use a FIXED max:
//   p = exp2(capL - K2_) = exp2(-2*K2_ / (ez+1)),  ez = exp2(score*C1_)
// Exact (same p/l ratios); kills all online-max machinery.
#define C1_ (2.0f * (0.08838834764831845f / 50.0f) * LOG2E_)
#define K2_ (50.0f * LOG2E_)
#define NK22_ (-2.0f * K2_)
#define EXP2F_(x) __builtin_amdgcn_exp2f(x)   // __exp2f collides w/ glibc macro

// ---------------- prepass: fp32 K/V -> bf16, head-major; V transposed ------
__global__ __launch_bounds__(256) void prep_kv(
    const float* __restrict__ K, const float* __restrict__ V,
    bf16_t* __restrict__ Kb, bf16_t* __restrict__ Vt)
{
  const int j0  = blockIdx.x * 64;
  const int kvh = blockIdx.y;
  const int b   = blockIdx.z;
  const int t   = threadIdx.x;
  const int j   = t >> 2;                // token row 0..63
  const int d0  = (t & 3) * 32;
  __shared__ bf16_t tl[128][72];

  // K: straight bf16 copy into [b][kvh][s][d]
  {
    const float* src = K + (size_t)(b * S_ + j0 + j) * KVD_ + kvh * D_ + d0;
    bf16_t* dst = Kb + ((size_t)(b * KVH_ + kvh) * S_ + j0 + j) * D_ + d0;
    #pragma unroll
    for (int c = 0; c < 4; ++c) {
      float4 f0 = *(const float4*)(src + c * 8);
      float4 f1 = *(const float4*)(src + c * 8 + 4);
      bf16x8 o = { (bf16_t)f0.x, (bf16_t)f0.y, (bf16_t)f0.z, (bf16_t)f0.w,
                   (bf16_t)f1.x, (bf16_t)f1.y, (bf16_t)f1.z, (bf16_t)f1.w };
      *(bf16x8*)(dst + c * 8) = o;
    }
  }
  // V: transpose via LDS into [b][kvh][d][s]
  {
    const float* src = V + (size_t)(b * S_ + j0 + j) * KVD_ + kvh * D_ + d0;
    #pragma unroll
    for (int c = 0; c < 8; ++c) {
      float4 f = *(const float4*)(src + c * 4);
      tl[d0 + c * 4 + 0][j] = (bf16_t)f.x;
      tl[d0 + c * 4 + 1][j] = (bf16_t)f.y;
      tl[d0 + c * 4 + 2][j] = (bf16_t)f.z;
      tl[d0 + c * 4 + 3][j] = (bf16_t)f.w;
    }
  }
  __syncthreads();
  {
    const int d = t >> 1, half = (t & 1) * 32;
    bf16_t* dst = Vt + ((size_t)(b * KVH_ + kvh) * D_ + d) * S_ + j0 + half;
    #pragma unroll
    for (int c = 0; c < 4; ++c)
      *(bf16x8*)(dst + c * 8) = *(bf16x8*)&tl[d][half + c * 8];
  }
}

// ---------------- attention ------------------------------------------------
// wg = (b, kvh, 32-row q-tile), 512 thr = 8 waves = 4 heads x 2 row-blocks.
// KVBLK=32, LDS 40KB. Reg-staged double buffer: LINEAR coalesced global
// dwordx4 loads issued at tile top (latency hides under compute), swizzled
// ds_write_b128 after compute, ONE barrier per tile publishes the buffer.
// Fixed-max softmax (softcap bound) removes online-max machinery.
// Swizzle keys: 128-wide rows use ^(row&15) on 16-B chunks (full 32 banks);
// 32-wide rows must use ^((row>>1)&3) so each 16-lane issue phase spreads
// its 8 same-half rows 2-per-bank-group (&3 keyed on row parity is 4-way).
// __launch_bounds__(512,4): VGPR cap 128 -> no spill (6 waves/SIMD spilled).
__global__ __launch_bounds__(512, 4) void attn_fwd(
    const float* __restrict__ Q, const bf16_t* __restrict__ Kb,
    const bf16_t* __restrict__ Vt, float* __restrict__ Out)
{
  // XCD-aware bijective swizzle (1024 wgs % 8 == 0): each XCD gets a
  // contiguous 128-wg chunk = 4 whole (b,kvh) heads -> 2MB K/V per L2.
  const int fid = blockIdx.x + 32 * (blockIdx.y + 8 * (int)blockIdx.z);
  const int swz = (fid & 7) * 128 + (fid >> 3);
  const int i0  = (swz & 31) * 32;
  const int kvh = (swz >> 5) & 7;
  const int b   = swz >> 8;

  const int tid  = threadIdx.x;
  const int w    = tid >> 6;
  const int lane = tid & 63;
  const int m16  = lane & 15;
  const int quad = lane >> 4;
  const int g    = w & 3;
  const int rb   = w >> 2;
  const int h    = kvh * 4 + g;
  const int iw   = i0 + rb * 16;
  const int i    = iw + m16;
  const int sw16 = (m16 >> 1) & 3;        // 32-wide-row swizzle key

  __shared__ __align__(16) bf16_t KsB[2][32 * 128];  // 8KB x2
  __shared__ __align__(16) bf16_t VtB[2][128 * 32];  // 8KB x2
  __shared__ __align__(16) bf16_t PsB[8 * 16 * 32];  // 8KB

  // Q fragments (B-operand layout)
  bf16x8 qf[4];
  {
    const float* qp = Q + ((size_t)(b * S_ + iw + m16) * H_ + h) * D_;
    #pragma unroll
    for (int s = 0; s < 4; ++s) {
      const int d0 = 32 * s + 8 * quad;
      float4 f0 = *(const float4*)(qp + d0);
      float4 f1 = *(const float4*)(qp + d0 + 4);
      bf16x8 t = { (bf16_t)f0.x, (bf16_t)f0.y, (bf16_t)f0.z, (bf16_t)f0.w,
                   (bf16_t)f1.x, (bf16_t)f1.y, (bf16_t)f1.z, (bf16_t)f1.w };
      qf[s] = t;
    }
  }

  f32x4 O[8];
  #pragma unroll
  for (int c = 0; c < 8; ++c) O[c] = (f32x4){0.f, 0.f, 0.f, 0.f};
  f32x4 lacc = (f32x4){0.f, 0.f, 0.f, 0.f};

  const bf16_t* khead = Kb + (size_t)(b * KVH_ + kvh) * S_ * D_;
  const bf16_t* vhead = Vt + (size_t)(b * KVH_ + kvh) * D_ * S_;

  // per-thread staging geometry: chunk id = tid (512 x 16B = one K or V tile)
  const int krow = tid >> 4, kpos = tid & 15;     // K: 32 rows x 16 chunks
  const int vd   = tid >> 2, vpos = tid & 3;      // V^T: 128 rows x 4 chunks
  const bf16_t* ksrc = khead + (size_t)krow * D_ + kpos * 8;  // LINEAR global
  const bf16_t* vsrc = vhead + (size_t)vd * S_ + vpos * 8;
  const int koff = krow * 128 + ((kpos ^ (krow & 15)) << 3);        // swizzled
  const int voff = vd * 32 + ((vpos ^ ((vd >> 1) & 3)) << 3);       // LDS dst

  const int t_lo = (i0 >= WIN_) ? ((i0 - (WIN_ - 1)) >> 5) : 0;
  const int t_hi = i0 >> 5;

  // prologue: stage tile t_lo into buffer 0
  {
    int4 kr = *(const int4*)(ksrc + (size_t)t_lo * 32 * D_);
    int4 vr = *(const int4*)(vsrc + t_lo * 32);
    *(int4*)&KsB[0][koff] = kr;
    *(int4*)&VtB[0][voff] = vr;
  }
  __syncthreads();
  int buf = 0;

  for (int tb = t_lo; tb <= t_hi; ++tb) {
    const int j0  = tb * 32;
    const bool pre = (tb < t_hi);
    int4 kr, vr;
    if (pre) {   // issue next-tile loads NOW; vmcnt naturally drains at use
      kr = *(const int4*)(ksrc + (size_t)(j0 + 32) * D_);
      vr = *(const int4*)(vsrc + (j0 + 32));
    }

    if (!(j0 > iw + 15 || j0 + 31 < iw - (WIN_ - 1))) {
      const bool full = (j0 + 31 <= iw) && (iw + 15 - j0 < WIN_);
      const int pw = w * (16 * 32);

      // ---- S^T = K·Q^T, fused softcap -> p (fixed max) -> P to LDS ----
      #pragma unroll
      for (int t4 = 0; t4 < 2; ++t4) {
        f32x4 acc = (f32x4){0.f, 0.f, 0.f, 0.f};
        const int row = 16 * t4 + m16;
        __builtin_amdgcn_s_setprio(1);
        #pragma unroll
        for (int s = 0; s < 4; ++s) {
          bf16x8 a = *(const bf16x8*)&KsB[buf][row * 128 + (((quad + 4 * s) ^ m16) << 3)];
          acc = __builtin_amdgcn_mfma_f32_16x16x32_bf16(a, qf[s], acc, 0, 0, 0);
        }
        __builtin_amdgcn_s_setprio(0);
        bf16x4 pk;
        #pragma unroll
        for (int r = 0; r < 4; ++r) {
          float ez = EXP2F_(acc[r] * C1_);
          float p  = EXP2F_(NK22_ * __builtin_amdgcn_rcpf(ez + 1.f));
          if (!full) {
            const int j = j0 + t4 * 16 + 4 * quad + r;
            p = ((j <= i) && (i - j < WIN_)) ? p : 0.f;
          }
          lacc[r] += p;
          pk[r] = (bf16_t)p;
        }
        const int ch = (2 * t4 + (quad >> 1)) ^ sw16;
        *(bf16x4*)&PsB[pw + m16 * 32 + ch * 8 + (quad & 1) * 4] = pk;
      }
      bf16x8 pa = *(const bf16x8*)&PsB[pw + m16 * 32 + ((quad ^ sw16) << 3)];

      // ---- O += P·V ----
      __builtin_amdgcn_s_setprio(1);
      #pragma unroll
      for (int c = 0; c < 8; ++c) {
        const int vrow = 16 * c + m16;
        bf16x8 v = *(const bf16x8*)&VtB[buf][vrow * 32 + ((quad ^ sw16) << 3)];
        O[c] = __builtin_amdgcn_mfma_f32_16x16x32_bf16(pa, v, O[c], 0, 0, 0);
      }
      __builtin_amdgcn_s_setprio(0);
    }

    if (pre) {   // write-late: regs -> swizzled LDS, published by the barrier
      *(int4*)&KsB[buf ^ 1][koff] = kr;
      *(int4*)&VtB[buf ^ 1][voff] = vr;
    }
    __syncthreads();
    buf ^= 1;
  }

  // ---- epilogue: one deferred row-sum reduce, then scale + store ----
  float l_run = lacc[0] + lacc[1] + lacc[2] + lacc[3];
  l_run += __shfl_xor(l_run, 16);
  l_run += __shfl_xor(l_run, 32);

  float* ob = Out + ((size_t)(b * S_ + iw) * H_ + h) * D_;
  #pragma unroll
  for (int r = 0; r < 4; ++r) {
    const int rr = 4 * quad + r;
    const float lr = __shfl(l_run, rr);
    const float linv = __builtin_amdgcn_rcpf(lr);
    float* po = ob + (size_t)rr * (H_ * D_);
    #pragma unroll
    for (int c = 0; c < 8; ++c) po[c * 16 + m16] = O[c][r] * linv;
  }
}

extern "C" void kernel_launch(void* const* d_in, const int* in_sizes, int n_in,
                              void* d_out, int out_size, void* d_ws, size_t ws_size,
                              hipStream_t stream) {
  const float* q = (const float*)d_in[0];
  const float* k = (const float*)d_in[1];
  const float* v = (const float*)d_in[2];
  float* out = (float*)d_out;
  const size_t nkv = (size_t)B_ * KVH_ * S_ * D_;   // 4.19M elems per tensor
  bf16_t *kb, *vt;
  if (ws_size >= 2 * nkv * sizeof(bf16_t)) {
    kb = (bf16_t*)d_ws; vt = kb + nkv;
  } else {
    // k_cache/v_cache are dead inputs (identity round-trip) - reuse as scratch
    kb = (bf16_t*)d_in[3]; vt = (bf16_t*)d_in[4];
  }
  prep_kv<<<dim3(S_ / 64, KVH_, B_), 256, 0, stream>>>(k, v, kb, vt);
  attn_fwd<<<dim3(S_ / 32, KVH_, B_), 512, 0, stream>>>(q, kb, vt, out);
}

// Round 3
// 209.996 us; speedup vs baseline: 1.4355x; 1.0035x over previous
//
#include <hip/hip_runtime.h>
#include <hip/hip_bf16.h>

typedef __bf16 bf16_t;
typedef bf16_t bf16x8 __attribute__((ext_vector_type(8)));
typedef bf16_t bf16x4 __attribute__((ext_vector_type(4)));
typedef bf16_t bf16x2 __attribute__((ext_vector_type(2)));
typedef float f32x4 __attribute__((ext_vector_type(4)));

#define B_   4
#define S_   1024
#define H_   32
#define KVH_ 8
#define D_   128
#define WIN_ 512
#define KVD_ (KVH_ * D_)                 // 1024
#define LOG2E_ 1.4426950408889634f
// log2-domain softcap: capL = 50*log2e*tanh(score*scale/50)
// Softcap BOUNDS the logits (|capL| <= K2_), so softmax can use a FIXED max:
//   p = exp2(capL - K2_) = exp2(-2*K2_ / (ez+1)),  ez = exp2(score*C1_)
// Exact (same p/l ratios); kills all online-max machinery.
#define C1_ (2.0f * (0.08838834764831845f / 50.0f) * LOG2E_)
#define K2_ (50.0f * LOG2E_)
#define NK22_ (-2.0f * K2_)
#define EXP2F_(x) __builtin_amdgcn_exp2f(x)   // __exp2f collides w/ glibc macro

// ---------------- fused attention (single kernel, fp32-direct) -------------
// wg = (b, kvh, 32-row q-tile), 512 thr = 8 waves = 4 heads x 2 row-blocks.
// NO prepass, NO scratch, NO input writes: K and V are staged per-tile from
// the original fp32 tensors, converted to bf16 in registers during the
// write-late phase.  V's transpose happens at the LDS write (bf16x2 token-
// pair writes into the V^T layout).  This removes prep_kv + one launch and
// guarantees the harness never has to restore mutated inputs.
// Staging roles: waves 0-3 stage K (64B/lane fp32, coalesced; identical LDS
// layout as before, chunk ^(row&15)); waves 4-7 stage V (two consecutive
// token rows per lane, 8x 4B writes).  V^T chunk swizzle key extended to
// f(d) = ((d>>1)&3) ^ ((d>>4)&3)  so the d-dimension enters the bank index
// at the store side (~4-way instead of 16-way); PV read compensates with
// chunk = quad ^ sw16 ^ (c&3)  (c is compile-time in the unrolled loop).
__global__ __launch_bounds__(512, 4) void attn_fwd(
    const float* __restrict__ Q, const float* __restrict__ K,
    const float* __restrict__ V, float* __restrict__ Out)
{
  // XCD-aware bijective swizzle (1024 wgs % 8 == 0): each XCD gets a
  // contiguous 128-wg chunk = 4 whole (b,kvh) heads -> fp32 K/V ~4MB per L2.
  const int fid = blockIdx.x + 32 * (blockIdx.y + 8 * (int)blockIdx.z);
  const int swz = (fid & 7) * 128 + (fid >> 3);
  const int i0  = (swz & 31) * 32;
  const int kvh = (swz >> 5) & 7;
  const int b   = swz >> 8;

  const int tid  = threadIdx.x;
  const int w    = tid >> 6;
  const int lane = tid & 63;
  const int m16  = lane & 15;
  const int quad = lane >> 4;
  const int g    = w & 3;
  const int rb   = w >> 2;
  const int h    = kvh * 4 + g;
  const int iw   = i0 + rb * 16;
  const int i    = iw + m16;
  const int sw16 = (m16 >> 1) & 3;        // 32-wide-row swizzle key (low part)

  __shared__ __align__(16) bf16_t KsB[2][32 * 128];  // 8KB x2
  __shared__ __align__(16) bf16_t VtB[2][128 * 32];  // 8KB x2 (V^T)
  __shared__ __align__(16) bf16_t PsB[8 * 16 * 32];  // 8KB

  // Q fragments (B-operand layout)
  bf16x8 qf[4];
  {
    const float* qp = Q + ((size_t)(b * S_ + iw + m16) * H_ + h) * D_;
    #pragma unroll
    for (int s = 0; s < 4; ++s) {
      const int d0 = 32 * s + 8 * quad;
      float4 f0 = *(const float4*)(qp + d0);
      float4 f1 = *(const float4*)(qp + d0 + 4);
      bf16x8 t = { (bf16_t)f0.x, (bf16_t)f0.y, (bf16_t)f0.z, (bf16_t)f0.w,
                   (bf16_t)f1.x, (bf16_t)f1.y, (bf16_t)f1.z, (bf16_t)f1.w };
      qf[s] = t;
    }
  }

  f32x4 O[8];
  #pragma unroll
  for (int c = 0; c < 8; ++c) O[c] = (f32x4){0.f, 0.f, 0.f, 0.f};
  f32x4 lacc = (f32x4){0.f, 0.f, 0.f, 0.f};

  // ---- staging geometry (wave-uniform role split) ----
  const bool isK = (tid < 256);
  // K role: 256 thr, each 1 token row x 16 floats (64B contiguous)
  const int krow = tid >> 3;               // 0..31
  const int kseg = tid & 7;                // 16-float segment
  const float* ksrc = K + ((size_t)(b * S_ + krow) * KVH_ + kvh) * D_ + kseg * 16;
  const int koff0 = krow * 128 + (((2 * kseg)     ^ (krow & 15)) << 3);
  const int koff1 = krow * 128 + (((2 * kseg + 1) ^ (krow & 15)) << 3);
  // V role: 256 thr, each 2 consecutive token rows x 8 floats
  const int vt  = tid & 255;
  const int tv  = (vt >> 4) * 2;           // 0,2,..,30
  const int mpr = vt & 15;                 // d-chunk index (dv0 = mpr*8)
  const float* vsrc = V + ((size_t)(b * S_ + tv) * KVH_ + kvh) * D_ + mpr * 8;
  const int vbase = mpr * 256 + (tv & 7);  // (dv0+e)*32 = mpr*256 + e*32
  const int vch   = (tv >> 3) ^ ((mpr >> 1) & 3);

  const int t_lo = (i0 >= WIN_) ? ((i0 - (WIN_ - 1)) >> 5) : 0;
  const int t_hi = i0 >> 5;

  float4 r0, r1, r2, r3;
  auto loadStage = [&](int j0v) {
    if (isK) {
      const float* p = ksrc + (size_t)j0v * KVD_;
      r0 = *(const float4*)(p);      r1 = *(const float4*)(p + 4);
      r2 = *(const float4*)(p + 8);  r3 = *(const float4*)(p + 12);
    } else {
      const float* p = vsrc + (size_t)j0v * KVD_;
      r0 = *(const float4*)(p);            r1 = *(const float4*)(p + 4);
      r2 = *(const float4*)(p + KVD_);     r3 = *(const float4*)(p + KVD_ + 4);
    }
  };
  auto writeStage = [&](int bi) {
    if (isK) {
      bf16x8 lo = { (bf16_t)r0.x, (bf16_t)r0.y, (bf16_t)r0.z, (bf16_t)r0.w,
                    (bf16_t)r1.x, (bf16_t)r1.y, (bf16_t)r1.z, (bf16_t)r1.w };
      bf16x8 hi = { (bf16_t)r2.x, (bf16_t)r2.y, (bf16_t)r2.z, (bf16_t)r2.w,
                    (bf16_t)r3.x, (bf16_t)r3.y, (bf16_t)r3.z, (bf16_t)r3.w };
      *(bf16x8*)&KsB[bi][koff0] = lo;
      *(bf16x8*)&KsB[bi][koff1] = hi;
    } else {
      const float av[8] = { r0.x, r0.y, r0.z, r0.w, r1.x, r1.y, r1.z, r1.w };
      const float bv[8] = { r2.x, r2.y, r2.z, r2.w, r3.x, r3.y, r3.z, r3.w };
      #pragma unroll
      for (int e = 0; e < 8; ++e) {
        bf16x2 pr = { (bf16_t)av[e], (bf16_t)bv[e] };
        *(bf16x2*)&VtB[bi][vbase + e * 32 + ((vch ^ (e >> 1)) << 3)] = pr;
      }
    }
  };

  // prologue: stage tile t_lo into buffer 0
  loadStage(t_lo * 32);
  writeStage(0);
  __syncthreads();
  int buf = 0;

  for (int tb = t_lo; tb <= t_hi; ++tb) {
    const int j0  = tb * 32;
    const bool pre = (tb < t_hi);
    if (pre) loadStage(j0 + 32);   // issue-early; latency hides under compute

    if (!(j0 > iw + 15 || j0 + 31 < iw - (WIN_ - 1))) {
      const bool full = (j0 + 31 <= iw) && (iw + 15 - j0 < WIN_);
      const int pw = w * (16 * 32);

      // ---- S^T = K·Q^T, fused softcap -> p (fixed max) -> P to LDS ----
      #pragma unroll
      for (int t4 = 0; t4 < 2; ++t4) {
        f32x4 acc = (f32x4){0.f, 0.f, 0.f, 0.f};
        const int row = 16 * t4 + m16;
        __builtin_amdgcn_s_setprio(1);
        #pragma unroll
        for (int s = 0; s < 4; ++s) {
          bf16x8 a = *(const bf16x8*)&KsB[buf][row * 128 + (((quad + 4 * s) ^ m16) << 3)];
          acc = __builtin_amdgcn_mfma_f32_16x16x32_bf16(a, qf[s], acc, 0, 0, 0);
        }
        __builtin_amdgcn_s_setprio(0);
        bf16x4 pk;
        #pragma unroll
        for (int r = 0; r < 4; ++r) {
          float ez = EXP2F_(acc[r] * C1_);
          float p  = EXP2F_(NK22_ * __builtin_amdgcn_rcpf(ez + 1.f));
          if (!full) {
            const int j = j0 + t4 * 16 + 4 * quad + r;
            p = ((j <= i) && (i - j < WIN_)) ? p : 0.f;
          }
          lacc[r] += p;
          pk[r] = (bf16_t)p;
        }
        const int ch = (2 * t4 + (quad >> 1)) ^ sw16;
        *(bf16x4*)&PsB[pw + m16 * 32 + ch * 8 + (quad & 1) * 4] = pk;
      }
      bf16x8 pa = *(const bf16x8*)&PsB[pw + m16 * 32 + ((quad ^ sw16) << 3)];

      // ---- O += P·V  (V^T read: chunk = quad ^ sw16 ^ (c&3)) ----
      __builtin_amdgcn_s_setprio(1);
      #pragma unroll
      for (int c = 0; c < 8; ++c) {
        const int vrow = 16 * c + m16;
        bf16x8 v = *(const bf16x8*)&VtB[buf][vrow * 32 + (((quad ^ sw16) ^ (c & 3)) << 3)];
        O[c] = __builtin_amdgcn_mfma_f32_16x16x32_bf16(pa, v, O[c], 0, 0, 0);
      }
      __builtin_amdgcn_s_setprio(0);
    }

    if (pre) writeStage(buf ^ 1);  // write-late: cvt + swizzled LDS stores
    __syncthreads();
    buf ^= 1;
  }

  // ---- epilogue: one deferred row-sum reduce, then scale + store ----
  float l_run = lacc[0] + lacc[1] + lacc[2] + lacc[3];
  l_run += __shfl_xor(l_run, 16);
  l_run += __shfl_xor(l_run, 32);

  float* ob = Out + ((size_t)(b * S_ + iw) * H_ + h) * D_;
  #pragma unroll
  for (int r = 0; r < 4; ++r) {
    const int rr = 4 * quad + r;
    const float lr = __shfl(l_run, rr);
    const float linv = __builtin_amdgcn_rcpf(lr);
    float* po = ob + (size_t)rr * (H_ * D_);
    #pragma unroll
    for (int c = 0; c < 8; ++c) po[c * 16 + m16] = O[c][r] * linv;
  }
}

extern "C" void kernel_launch(void* const* d_in, const int* in_sizes, int n_in,
                              void* d_out, int out_size, void* d_ws, size_t ws_size,
                              hipStream_t stream) {
  const float* q = (const float*)d_in[0];
  const float* k = (const float*)d_in[1];
  const float* v = (const float*)d_in[2];
  float* out = (float*)d_out;
  // Single fused kernel: no prepass, no workspace, no input mutation.
  attn_fwd<<<dim3(S_ / 32, KVH_, B_), 512, 0, stream>>>(q, k, v, out);
}